// Round 11
// baseline (197.149 us; speedup 1.0000x reference)
//
#include <hip/hip_runtime.h>
#include <math.h>

#define NN 50000
#define NE 800000
#define D  128
#define CNT_BLOCKS 391    // ceil((NE/8)/256) — 8 edges/thread
#define GEMM_BLOCKS 782   // ceil(NN/64)
#define NROLES (CNT_BLOCKS + GEMM_BLOCKS)   // 1173
#define SC_BLOCKS 782     // ceil(NN*4/256)

typedef __attribute__((ext_vector_type(8))) short bf16x8;
typedef __attribute__((ext_vector_type(4))) float f32x4;

__device__ __forceinline__ unsigned short f32_to_bf16(float f) {
    unsigned u = __float_as_uint(f);
    u = u + 0x7FFFu + ((u >> 16) & 1u);   // RNE
    return (unsigned short)(u >> 16);
}

// fast tanh: 1 - 2*rcp(e^{2x}+1). Exact at saturation. |err| ~1e-6.
__device__ __forceinline__ float fast_tanh(float x) {
    float e = __expf(2.0f * x);
    return fmaf(-2.0f, __builtin_amdgcn_rcpf(e + 1.0f), 1.0f);
}

// 16 gathers forced in flight: loads + waitcnt in ONE volatile asm block.
// SGPR base + 32-bit voffset form; "=&v" keeps dsts distinct from addr regs.
#define GLD16(P, VO, BASE)                                              \
    asm volatile(                                                       \
        "global_load_dword %0, %16, %32\n\t"                            \
        "global_load_dword %1, %17, %32\n\t"                            \
        "global_load_dword %2, %18, %32\n\t"                            \
        "global_load_dword %3, %19, %32\n\t"                            \
        "global_load_dword %4, %20, %32\n\t"                            \
        "global_load_dword %5, %21, %32\n\t"                            \
        "global_load_dword %6, %22, %32\n\t"                            \
        "global_load_dword %7, %23, %32\n\t"                            \
        "global_load_dword %8, %24, %32\n\t"                            \
        "global_load_dword %9, %25, %32\n\t"                            \
        "global_load_dword %10, %26, %32\n\t"                           \
        "global_load_dword %11, %27, %32\n\t"                           \
        "global_load_dword %12, %28, %32\n\t"                           \
        "global_load_dword %13, %29, %32\n\t"                           \
        "global_load_dword %14, %30, %32\n\t"                           \
        "global_load_dword %15, %31, %32\n\t"                           \
        "s_waitcnt vmcnt(0)"                                            \
        : "=&v"(P[0]),  "=&v"(P[1]),  "=&v"(P[2]),  "=&v"(P[3]),        \
          "=&v"(P[4]),  "=&v"(P[5]),  "=&v"(P[6]),  "=&v"(P[7]),        \
          "=&v"(P[8]),  "=&v"(P[9]),  "=&v"(P[10]), "=&v"(P[11]),       \
          "=&v"(P[12]), "=&v"(P[13]), "=&v"(P[14]), "=&v"(P[15])        \
        : "v"(VO[0]),  "v"(VO[1]),  "v"(VO[2]),  "v"(VO[3]),            \
          "v"(VO[4]),  "v"(VO[5]),  "v"(VO[6]),  "v"(VO[7]),            \
          "v"(VO[8]),  "v"(VO[9]),  "v"(VO[10]), "v"(VO[11]),           \
          "v"(VO[12]), "v"(VO[13]), "v"(VO[14]), "v"(VO[15]),           \
          "s"(BASE))

// ---- K0: deg zero; W bf16-frag pack (block 0); zb sentinel row ------------
__global__ __launch_bounds__(256) void k_init(
        const float* __restrict__ Wg, int* __restrict__ deg,
        unsigned short* __restrict__ wpk, unsigned short* __restrict__ zb) {
    int tid = threadIdx.x;
    int idx = blockIdx.x * 256 + tid;

    if (idx < NN / 4) ((int4*)deg)[idx] = (int4){0, 0, 0, 0};

    if (blockIdx.x == 0) {
        // frag = nt*256 + kt*64 + quad*16 + lo, elem j = k&7 (verified layout)
#pragma unroll 8
        for (int i = 0; i < 64; i++) {
            int o = i * 256 + tid;
            int j = o & 7, frag = o >> 3;
            int lo = frag & 15, quad = (frag >> 4) & 3;
            int kt = (frag >> 6) & 3, nt = frag >> 8;
            wpk[o] = f32_to_bf16(Wg[(kt * 32 + quad * 8 + j) * 128 + nt * 16 + lo]);
        }
    }
    if (blockIdx.x == 1 && tid < 64)
        ((unsigned*)(zb + (size_t)NN * D))[tid] = 0u;   // sentinel row = 0
}

// ---- K1: count role (391 blocks, 8 edges/thread -> 8 atomics in flight,
// ushort ELL halves scatter footprint) + GEMM role (782 blocks, zf = hW).
// Out-tail zeroing spread over ALL blocks with int4 stores. -----------------
__global__ __launch_bounds__(256) void k_count_gemm(
        const float* __restrict__ h, const uint4* __restrict__ wpk4,
        const int* __restrict__ ei, int* __restrict__ deg,
        unsigned short* __restrict__ ell, float* __restrict__ zf,
        int* __restrict__ outtail, int tailN) {
    int tid = threadIdx.x;
    int bid = blockIdx.x;

    // out-tail zeroing: all blocks, int4-wide (GEMM blocks finish early
    // and absorb most of it; was 16 scalar stores/thread in count role)
    {
        int gt = bid * 256 + tid;
        int tail4 = tailN >> 2;
        for (int i = gt; i < tail4; i += NROLES * 256)
            ((int4*)outtail)[i] = (int4){0, 0, 0, 0};
        if (gt == 0)
            for (int k2 = tail4 << 2; k2 < tailN; k2++) outtail[k2] = 0;
    }

    if (bid < CNT_BLOCKS) {
        int g = bid * 256 + tid;          // edge octet id
        if (g < NE / 8) {
            int4 sa = ((const int4*)ei)[2 * g];
            int4 sb = ((const int4*)ei)[2 * g + 1];
            int4 da = ((const int4*)(ei + NE))[2 * g];
            int4 db = ((const int4*)(ei + NE))[2 * g + 1];
            int r0 = atomicAdd(&deg[da.x], 1);
            int r1 = atomicAdd(&deg[da.y], 1);
            int r2 = atomicAdd(&deg[da.z], 1);
            int r3 = atomicAdd(&deg[da.w], 1);
            int r4 = atomicAdd(&deg[db.x], 1);
            int r5 = atomicAdd(&deg[db.y], 1);
            int r6 = atomicAdd(&deg[db.z], 1);
            int r7 = atomicAdd(&deg[db.w], 1);
            // deg>64 impossible here (Binomial mean 16, 12 sigma); guard anyway
            if (r0 < 64) ell[(size_t)da.x * 64 + r0] = (unsigned short)sa.x;
            if (r1 < 64) ell[(size_t)da.y * 64 + r1] = (unsigned short)sa.y;
            if (r2 < 64) ell[(size_t)da.z * 64 + r2] = (unsigned short)sa.z;
            if (r3 < 64) ell[(size_t)da.w * 64 + r3] = (unsigned short)sa.w;
            if (r4 < 64) ell[(size_t)db.x * 64 + r4] = (unsigned short)sb.x;
            if (r5 < 64) ell[(size_t)db.y * 64 + r5] = (unsigned short)sb.y;
            if (r6 < 64) ell[(size_t)db.z * 64 + r6] = (unsigned short)sb.z;
            if (r7 < 64) ell[(size_t)db.w * 64 + r7] = (unsigned short)sb.w;
        }
        return;
    }

    int gid = bid - CNT_BLOCKS;
    int w = tid >> 6, lane = tid & 63;
    int quad = lane >> 4, lo = lane & 15;
    int rowBase = gid * 64 + w * 16;
    int rowA = rowBase + lo; if (rowA > NN - 1) rowA = NN - 1;
    const float4* h4 = (const float4*)h;

    bf16x8 af[4];
#pragma unroll
    for (int kt = 0; kt < 4; kt++) {
        float4 u = h4[(size_t)rowA * 32 + kt * 8 + quad * 2];
        float4 v = h4[(size_t)rowA * 32 + kt * 8 + quad * 2 + 1];
        bf16x8 a;
        a[0] = (short)f32_to_bf16(u.x); a[1] = (short)f32_to_bf16(u.y);
        a[2] = (short)f32_to_bf16(u.z); a[3] = (short)f32_to_bf16(u.w);
        a[4] = (short)f32_to_bf16(v.x); a[5] = (short)f32_to_bf16(v.y);
        a[6] = (short)f32_to_bf16(v.z); a[7] = (short)f32_to_bf16(v.w);
        af[kt] = a;
    }

    f32x4 acc[8];
#pragma unroll
    for (int nt = 0; nt < 8; nt++) acc[nt] = (f32x4){0.f, 0.f, 0.f, 0.f};

#pragma unroll
    for (int kt = 0; kt < 4; kt++)
#pragma unroll
        for (int nt = 0; nt < 8; nt++) {
            uint4 tb = wpk4[nt * 256 + kt * 64 + lane];   // coalesced, L1-hit
            acc[nt] = __builtin_amdgcn_mfma_f32_16x16x32_bf16(
                af[kt], __builtin_bit_cast(bf16x8, tb), acc[nt], 0, 0, 0);
        }

#pragma unroll
    for (int reg = 0; reg < 4; reg++) {
        int row = rowBase + quad * 4 + reg;
        if (row < NN) {
#pragma unroll
            for (int nt = 0; nt < 8; nt++)
                zf[(size_t)row * D + nt * 16 + lo] = acc[nt][reg];
        }
    }
}

// ---- K2: pure streaming scale: zb = bf16(zf * rsqrt(deg+1)) ---------------
__global__ __launch_bounds__(256) void k_scale(
        const int* __restrict__ deg, const float* __restrict__ zf,
        unsigned short* __restrict__ zb) {
    int g = blockIdx.x * 256 + threadIdx.x;
    if (g < NN * 4) {
        int row = g >> 2, seg = g & 3;
        float dn = rsqrtf((float)deg[row] + 1.0f);   // +1 self loop
        const float4* src = (const float4*)(zf + (size_t)row * D + seg * 32);
        uint4* dst = (uint4*)(zb + (size_t)row * D + seg * 32);
#pragma unroll
        for (int i = 0; i < 4; i++) {
            float4 a = src[i * 2], bb = src[i * 2 + 1];
            uint4 o;
            o.x = (unsigned)f32_to_bf16(a.x * dn) | ((unsigned)f32_to_bf16(a.y * dn) << 16);
            o.y = (unsigned)f32_to_bf16(a.z * dn) | ((unsigned)f32_to_bf16(a.w * dn) << 16);
            o.z = (unsigned)f32_to_bf16(bb.x * dn) | ((unsigned)f32_to_bf16(bb.y * dn) << 16);
            o.w = (unsigned)f32_to_bf16(bb.z * dn) | ((unsigned)f32_to_bf16(bb.w * dn) << 16);
            dst[i] = o;
        }
    }
}

// ---- K3: gather + LN + tanh over ushort-ELL rows. Slot-order summation
// unchanged -> bit-identical output. ----------------------------------------
__global__ __launch_bounds__(256) void k_gather_ln(
        const int* __restrict__ deg, const unsigned short* __restrict__ ell,
        const unsigned* __restrict__ zbu,
        const float* __restrict__ bias, const float* __restrict__ gamma,
        const float* __restrict__ beta, float* __restrict__ out) {
    int tid = threadIdx.x;
    int w = tid >> 6, lane = tid & 63;
    int rowBase = blockIdx.x * 16 + w * 4;
    unsigned lane4 = (unsigned)(lane << 2);

    int m0[4]; float dn[4]; unsigned selfz[4]; int v[4];
#pragma unroll
    for (int r = 0; r < 4; r++) {
        int row = rowBase + r;
        int dg = __builtin_amdgcn_readfirstlane(deg[row]);
        dn[r] = rsqrtf((float)dg + 1.0f);
        m0[r] = (dg > 64) ? 64 : dg;
        selfz[r] = zbu[(size_t)row * 64 + lane];
        int t0 = (int)ell[(size_t)row * 64 + lane];   // 128B coalesced row
        v[r] = (lane < m0[r]) ? t0 : NN;              // pad -> zero sentinel
    }

    float ax[4], ay[4];
#pragma unroll
    for (int r = 0; r < 4; r++) {
        ax[r] = __uint_as_float(selfz[r] << 16);
        ay[r] = __uint_as_float(selfz[r] & 0xFFFF0000u);
    }

    float2 x[4];
#pragma unroll
    for (int r = 0; r < 4; r++) {
        int nb = (m0[r] + 15) >> 4;              // uniform per row
        for (int jb = 0; jb < nb; ++jb) {
            int j = jb << 4;
            unsigned vo[16], p[16];
#pragma unroll
            for (int q = 0; q < 16; q++) {
                int sq = __builtin_amdgcn_readlane(v[r], j + q);
                vo[q] = ((unsigned)sq << 8) + lane4;   // byte offset in zb
            }
            GLD16(p, vo, zbu);
#pragma unroll
            for (int q = 0; q < 16; q++) {
                ax[r] += __uint_as_float(p[q] << 16);
                ay[r] += __uint_as_float(p[q] & 0xFFFF0000u);
            }
        }
        x[r].x = ax[r] * dn[r];
        x[r].y = ay[r] * dn[r];
    }

    float2 bi = ((const float2*)bias)[lane];
    float2 ga = ((const float2*)gamma)[lane];
    float2 be = ((const float2*)beta)[lane];
#pragma unroll
    for (int r = 0; r < 4; r++) {
        int row = rowBase + r;
        float y0 = x[r].x + bi.x;
        float y1 = x[r].y + bi.y;
        float s = y0 + y1;
#pragma unroll
        for (int off = 32; off > 0; off >>= 1) s += __shfl_xor(s, off, 64);
        float m = s * (1.0f / 128.0f);
        float v0f = y0 - m, v1f = y1 - m;
        float vs = v0f * v0f + v1f * v1f;
#pragma unroll
        for (int off = 32; off > 0; off >>= 1) vs += __shfl_xor(vs, off, 64);
        float rstd = rsqrtf(vs * (1.0f / 128.0f) + 1e-5f);
        float2 o;
        o.x = fast_tanh(v0f * rstd * ga.x + be.x);
        o.y = fast_tanh(v1f * rstd * ga.y + be.y);
        *(float2*)&out[(size_t)row * D + lane * 2] = o;
    }
}

extern "C" void kernel_launch(void* const* d_in, const int* in_sizes, int n_in,
                              void* d_out, int out_size, void* d_ws, size_t ws_size,
                              hipStream_t stream) {
    // inputs: t, h, edge_index, batch_size, W, b, gamma, beta
    const float* h     = (const float*)d_in[1];
    const int*   ei    = (const int*)  d_in[2];
    const float* Wg    = (const float*)d_in[4];
    const float* b     = (const float*)d_in[5];
    const float* gamma = (const float*)d_in[6];
    const float* beta  = (const float*)d_in[7];
    float* out = (float*)d_out;

    // workspace layout (~45 MB): wpk | deg | ell(ushort) | zb | zf
    char* wsb = (char*)d_ws;
    unsigned short* wpk = (unsigned short*)(wsb);            // 32768 B
    int*            deg = (int*)(wsb + 32768);               // NN ints -> 232768
    unsigned short* ell = (unsigned short*)(wsb + 232768);   // NN*64 ushorts -> 6632768
    unsigned short* zb  = (unsigned short*)(wsb + 6632768);  // (NN+1)*128 ushorts -> 19433024
    float*          zf  = (float*)(wsb + 19433024);          // NN*128 floats -> 45033024

    int tailN = out_size - NN * D;                 // int-zeros tail of d_out
    int* outtail = (int*)(out + (size_t)NN * D);

    k_init       <<<64,        256, 0, stream>>>(Wg, deg, wpk, zb);
    k_count_gemm <<<NROLES,    256, 0, stream>>>(h, (const uint4*)wpk, ei, deg, ell, zf, outtail, tailN);
    k_scale      <<<SC_BLOCKS, 256, 0, stream>>>(deg, zf, zb);
    k_gather_ln  <<<NN / 16,   256, 0, stream>>>(deg, ell, (const unsigned*)zb, b, gamma, beta, out);
}

// Round 12
// 195.092 us; speedup vs baseline: 1.0105x; 1.0105x over previous
//
#include <hip/hip_runtime.h>
#include <math.h>

#define NN 50000
#define NE 800000
#define D  128
#define CNT_BLOCKS 1564   // ceil((NE/2)/256)=1563 used + 1 idle; 2 edges/thread
#define GEMM_BLOCKS 782   // ceil(NN/64)
#define NROLES 2346       // 2:1 interleave via bid%3 (2345 = 3*781+2 covers gemm 781)
#define SC_BLOCKS 782     // ceil(NN*4/256)

typedef __attribute__((ext_vector_type(8))) short bf16x8;
typedef __attribute__((ext_vector_type(4))) float f32x4;

__device__ __forceinline__ unsigned short f32_to_bf16(float f) {
    unsigned u = __float_as_uint(f);
    u = u + 0x7FFFu + ((u >> 16) & 1u);   // RNE
    return (unsigned short)(u >> 16);
}

// fast tanh: 1 - 2*rcp(e^{2x}+1). Exact at saturation. |err| ~1e-6.
__device__ __forceinline__ float fast_tanh(float x) {
    float e = __expf(2.0f * x);
    return fmaf(-2.0f, __builtin_amdgcn_rcpf(e + 1.0f), 1.0f);
}

// 16 gathers forced in flight: loads + waitcnt in ONE volatile asm block.
// SGPR base + 32-bit voffset form; "=&v" keeps dsts distinct from addr regs.
#define GLD16(P, VO, BASE)                                              \
    asm volatile(                                                       \
        "global_load_dword %0, %16, %32\n\t"                            \
        "global_load_dword %1, %17, %32\n\t"                            \
        "global_load_dword %2, %18, %32\n\t"                            \
        "global_load_dword %3, %19, %32\n\t"                            \
        "global_load_dword %4, %20, %32\n\t"                            \
        "global_load_dword %5, %21, %32\n\t"                            \
        "global_load_dword %6, %22, %32\n\t"                            \
        "global_load_dword %7, %23, %32\n\t"                            \
        "global_load_dword %8, %24, %32\n\t"                            \
        "global_load_dword %9, %25, %32\n\t"                            \
        "global_load_dword %10, %26, %32\n\t"                           \
        "global_load_dword %11, %27, %32\n\t"                           \
        "global_load_dword %12, %28, %32\n\t"                           \
        "global_load_dword %13, %29, %32\n\t"                           \
        "global_load_dword %14, %30, %32\n\t"                           \
        "global_load_dword %15, %31, %32\n\t"                           \
        "s_waitcnt vmcnt(0)"                                            \
        : "=&v"(P[0]),  "=&v"(P[1]),  "=&v"(P[2]),  "=&v"(P[3]),        \
          "=&v"(P[4]),  "=&v"(P[5]),  "=&v"(P[6]),  "=&v"(P[7]),        \
          "=&v"(P[8]),  "=&v"(P[9]),  "=&v"(P[10]), "=&v"(P[11]),       \
          "=&v"(P[12]), "=&v"(P[13]), "=&v"(P[14]), "=&v"(P[15])        \
        : "v"(VO[0]),  "v"(VO[1]),  "v"(VO[2]),  "v"(VO[3]),            \
          "v"(VO[4]),  "v"(VO[5]),  "v"(VO[6]),  "v"(VO[7]),            \
          "v"(VO[8]),  "v"(VO[9]),  "v"(VO[10]), "v"(VO[11]),           \
          "v"(VO[12]), "v"(VO[13]), "v"(VO[14]), "v"(VO[15]),           \
          "s"(BASE))

// ---- K0: deg zero; W bf16-frag pack (block 0); zb sentinel row ------------
__global__ __launch_bounds__(256) void k_init(
        const float* __restrict__ Wg, int* __restrict__ deg,
        unsigned short* __restrict__ wpk, unsigned short* __restrict__ zb) {
    int tid = threadIdx.x;
    int idx = blockIdx.x * 256 + tid;

    if (idx < NN / 4) ((int4*)deg)[idx] = (int4){0, 0, 0, 0};

    if (blockIdx.x == 0) {
        // frag = nt*256 + kt*64 + quad*16 + lo, elem j = k&7 (verified layout)
#pragma unroll 8
        for (int i = 0; i < 64; i++) {
            int o = i * 256 + tid;
            int j = o & 7, frag = o >> 3;
            int lo = frag & 15, quad = (frag >> 4) & 3;
            int kt = (frag >> 6) & 3, nt = frag >> 8;
            wpk[o] = f32_to_bf16(Wg[(kt * 32 + quad * 8 + j) * 128 + nt * 16 + lo]);
        }
    }
    if (blockIdx.x == 1 && tid < 64)
        ((unsigned*)(zb + (size_t)NN * D))[tid] = 0u;   // sentinel row = 0
}

// ---- K1: count role FINE-SPLIT (1564 blocks x 2 edges/thread, 2:1
// interleave with gemm via bid%3) — count phase is atomic-LATENCY-bound,
// needs wave parallelism (round-11 coarsening regressed). int ELL (ushort
// gave no write reduction). GEMM role unchanged (zf = hW, unscaled). --------
__global__ __launch_bounds__(256) void k_count_gemm(
        const float* __restrict__ h, const uint4* __restrict__ wpk4,
        const int* __restrict__ ei, int* __restrict__ deg,
        int* __restrict__ ell, float* __restrict__ zf,
        int* __restrict__ outtail, int tailN) {
    int tid = threadIdx.x;
    int bid = blockIdx.x;

    // out-tail zeroing: all blocks, int4-wide
    {
        int gt = bid * 256 + tid;
        int tail4 = tailN >> 2;
        for (int i = gt; i < tail4; i += NROLES * 256)
            ((int4*)outtail)[i] = (int4){0, 0, 0, 0};
        if (gt == 0)
            for (int k2 = tail4 << 2; k2 < tailN; k2++) outtail[k2] = 0;
    }

    int rem = bid % 3;
    if (rem != 2) {
        // ---- count role: cnt = 2*(bid/3) + rem, 2 edges/thread ----
        int cnt = 2 * (bid / 3) + rem;
        int g = cnt * 256 + tid;           // edge-pair id
        if (g < NE / 2) {
            int2 s2 = ((const int2*)ei)[g];
            int2 d2 = ((const int2*)(ei + NE))[g];
            int r0 = atomicAdd(&deg[d2.x], 1);
            int r1 = atomicAdd(&deg[d2.y], 1);
            // deg>64 impossible here (Binomial mean 16, 12 sigma); guard anyway
            if (r0 < 64) ell[(size_t)d2.x * 64 + r0] = s2.x;
            if (r1 < 64) ell[(size_t)d2.y * 64 + r1] = s2.y;
        }
        return;
    }

    // ---- GEMM role: gid = bid/3 in [0, 782) ----
    int gid = bid / 3;
    int w = tid >> 6, lane = tid & 63;
    int quad = lane >> 4, lo = lane & 15;
    int rowBase = gid * 64 + w * 16;
    int rowA = rowBase + lo; if (rowA > NN - 1) rowA = NN - 1;
    const float4* h4 = (const float4*)h;

    bf16x8 af[4];
#pragma unroll
    for (int kt = 0; kt < 4; kt++) {
        float4 u = h4[(size_t)rowA * 32 + kt * 8 + quad * 2];
        float4 v = h4[(size_t)rowA * 32 + kt * 8 + quad * 2 + 1];
        bf16x8 a;
        a[0] = (short)f32_to_bf16(u.x); a[1] = (short)f32_to_bf16(u.y);
        a[2] = (short)f32_to_bf16(u.z); a[3] = (short)f32_to_bf16(u.w);
        a[4] = (short)f32_to_bf16(v.x); a[5] = (short)f32_to_bf16(v.y);
        a[6] = (short)f32_to_bf16(v.z); a[7] = (short)f32_to_bf16(v.w);
        af[kt] = a;
    }

    f32x4 acc[8];
#pragma unroll
    for (int nt = 0; nt < 8; nt++) acc[nt] = (f32x4){0.f, 0.f, 0.f, 0.f};

#pragma unroll
    for (int kt = 0; kt < 4; kt++)
#pragma unroll
        for (int nt = 0; nt < 8; nt++) {
            uint4 tb = wpk4[nt * 256 + kt * 64 + lane];   // coalesced, L1-hit
            acc[nt] = __builtin_amdgcn_mfma_f32_16x16x32_bf16(
                af[kt], __builtin_bit_cast(bf16x8, tb), acc[nt], 0, 0, 0);
        }

#pragma unroll
    for (int reg = 0; reg < 4; reg++) {
        int row = rowBase + quad * 4 + reg;
        if (row < NN) {
#pragma unroll
            for (int nt = 0; nt < 8; nt++)
                zf[(size_t)row * D + nt * 16 + lo] = acc[nt][reg];
        }
    }
}

// ---- K2: pure streaming scale: zb = bf16(zf * rsqrt(deg+1)) ---------------
__global__ __launch_bounds__(256) void k_scale(
        const int* __restrict__ deg, const float* __restrict__ zf,
        unsigned short* __restrict__ zb) {
    int g = blockIdx.x * 256 + threadIdx.x;
    if (g < NN * 4) {
        int row = g >> 2, seg = g & 3;
        float dn = rsqrtf((float)deg[row] + 1.0f);   // +1 self loop
        const float4* src = (const float4*)(zf + (size_t)row * D + seg * 32);
        uint4* dst = (uint4*)(zb + (size_t)row * D + seg * 32);
#pragma unroll
        for (int i = 0; i < 4; i++) {
            float4 a = src[i * 2], bb = src[i * 2 + 1];
            uint4 o;
            o.x = (unsigned)f32_to_bf16(a.x * dn) | ((unsigned)f32_to_bf16(a.y * dn) << 16);
            o.y = (unsigned)f32_to_bf16(a.z * dn) | ((unsigned)f32_to_bf16(a.w * dn) << 16);
            o.z = (unsigned)f32_to_bf16(bb.x * dn) | ((unsigned)f32_to_bf16(bb.y * dn) << 16);
            o.w = (unsigned)f32_to_bf16(bb.z * dn) | ((unsigned)f32_to_bf16(bb.w * dn) << 16);
            dst[i] = o;
        }
    }
}

// ---- K3: gather + LN + tanh over int-ELL rows (round-10 proven) -----------
__global__ __launch_bounds__(256) void k_gather_ln(
        const int* __restrict__ deg, const int* __restrict__ ell,
        const unsigned* __restrict__ zbu,
        const float* __restrict__ bias, const float* __restrict__ gamma,
        const float* __restrict__ beta, float* __restrict__ out) {
    int tid = threadIdx.x;
    int w = tid >> 6, lane = tid & 63;
    int rowBase = blockIdx.x * 16 + w * 4;
    unsigned lane4 = (unsigned)(lane << 2);

    int m0[4]; float dn[4]; unsigned selfz[4]; int v[4];
#pragma unroll
    for (int r = 0; r < 4; r++) {
        int row = rowBase + r;
        int dg = __builtin_amdgcn_readfirstlane(deg[row]);
        dn[r] = rsqrtf((float)dg + 1.0f);
        m0[r] = (dg > 64) ? 64 : dg;
        selfz[r] = zbu[(size_t)row * 64 + lane];
        int t0 = ell[(size_t)row * 64 + lane];   // coalesced 256B row
        v[r] = (lane < m0[r]) ? t0 : NN;         // pad -> zero sentinel row
    }

    float ax[4], ay[4];
#pragma unroll
    for (int r = 0; r < 4; r++) {
        ax[r] = __uint_as_float(selfz[r] << 16);
        ay[r] = __uint_as_float(selfz[r] & 0xFFFF0000u);
    }

    float2 x[4];
#pragma unroll
    for (int r = 0; r < 4; r++) {
        int nb = (m0[r] + 15) >> 4;              // uniform per row
        for (int jb = 0; jb < nb; ++jb) {
            int j = jb << 4;
            unsigned vo[16], p[16];
#pragma unroll
            for (int q = 0; q < 16; q++) {
                int sq = __builtin_amdgcn_readlane(v[r], j + q);
                vo[q] = ((unsigned)sq << 8) + lane4;   // byte offset in zb
            }
            GLD16(p, vo, zbu);
#pragma unroll
            for (int q = 0; q < 16; q++) {
                ax[r] += __uint_as_float(p[q] << 16);
                ay[r] += __uint_as_float(p[q] & 0xFFFF0000u);
            }
        }
        x[r].x = ax[r] * dn[r];
        x[r].y = ay[r] * dn[r];
    }

    float2 bi = ((const float2*)bias)[lane];
    float2 ga = ((const float2*)gamma)[lane];
    float2 be = ((const float2*)beta)[lane];
#pragma unroll
    for (int r = 0; r < 4; r++) {
        int row = rowBase + r;
        float y0 = x[r].x + bi.x;
        float y1 = x[r].y + bi.y;
        float s = y0 + y1;
#pragma unroll
        for (int off = 32; off > 0; off >>= 1) s += __shfl_xor(s, off, 64);
        float m = s * (1.0f / 128.0f);
        float v0f = y0 - m, v1f = y1 - m;
        float vs = v0f * v0f + v1f * v1f;
#pragma unroll
        for (int off = 32; off > 0; off >>= 1) vs += __shfl_xor(vs, off, 64);
        float rstd = rsqrtf(vs * (1.0f / 128.0f) + 1e-5f);
        float2 o;
        o.x = fast_tanh(v0f * rstd * ga.x + be.x);
        o.y = fast_tanh(v1f * rstd * ga.y + be.y);
        *(float2*)&out[(size_t)row * D + lane * 2] = o;
    }
}

extern "C" void kernel_launch(void* const* d_in, const int* in_sizes, int n_in,
                              void* d_out, int out_size, void* d_ws, size_t ws_size,
                              hipStream_t stream) {
    // inputs: t, h, edge_index, batch_size, W, b, gamma, beta
    const float* h     = (const float*)d_in[1];
    const int*   ei    = (const int*)  d_in[2];
    const float* Wg    = (const float*)d_in[4];
    const float* b     = (const float*)d_in[5];
    const float* gamma = (const float*)d_in[6];
    const float* beta  = (const float*)d_in[7];
    float* out = (float*)d_out;

    // workspace layout (~51.4 MB): wpk | deg | ell(int) | zb | zf
    char* wsb = (char*)d_ws;
    unsigned short* wpk = (unsigned short*)(wsb);            // 32768 B
    int*            deg = (int*)(wsb + 32768);               // NN ints -> 232768
    int*            ell = (int*)(wsb + 232768);              // NN*64 ints -> 13032768
    unsigned short* zb  = (unsigned short*)(wsb + 13032768); // (NN+1)*128 ushorts -> 25833024
    float*          zf  = (float*)(wsb + 25833024);          // NN*128 floats -> 51433024

    int tailN = out_size - NN * D;                 // int-zeros tail of d_out
    int* outtail = (int*)(out + (size_t)NN * D);

    k_init       <<<64,        256, 0, stream>>>(Wg, deg, wpk, zb);
    k_count_gemm <<<NROLES,    256, 0, stream>>>(h, (const uint4*)wpk, ei, deg, ell, zf, outtail, tailN);
    k_scale      <<<SC_BLOCKS, 256, 0, stream>>>(deg, zf, zb);
    k_gather_ln  <<<NN / 16,   256, 0, stream>>>(deg, ell, (const unsigned*)zb, b, gamma, beta, out);
}

// Round 13
// 188.529 us; speedup vs baseline: 1.0457x; 1.0348x over previous
//
#include <hip/hip_runtime.h>
#include <math.h>

#define NN 50000
#define NE 800000
#define D  128
#define CNT_BLOCKS 3125   // NE / 256 — 1 edge/thread, max wave parallelism
#define GEMM_BLOCKS 782   // ceil(NN/64)

typedef __attribute__((ext_vector_type(8))) short bf16x8;
typedef __attribute__((ext_vector_type(4))) float f32x4;

__device__ __forceinline__ unsigned short f32_to_bf16(float f) {
    unsigned u = __float_as_uint(f);
    u = u + 0x7FFFu + ((u >> 16) & 1u);   // RNE
    return (unsigned short)(u >> 16);
}

// fast tanh: 1 - 2*rcp(e^{2x}+1). Exact at saturation. |err| ~1e-6.
__device__ __forceinline__ float fast_tanh(float x) {
    float e = __expf(2.0f * x);
    return fmaf(-2.0f, __builtin_amdgcn_rcpf(e + 1.0f), 1.0f);
}

// 16 gathers forced in flight: loads + waitcnt in ONE volatile asm block.
// SGPR base + 32-bit voffset form; "=&v" keeps dsts distinct from addr regs.
#define GLD16(P, VO, BASE)                                              \
    asm volatile(                                                       \
        "global_load_dword %0, %16, %32\n\t"                            \
        "global_load_dword %1, %17, %32\n\t"                            \
        "global_load_dword %2, %18, %32\n\t"                            \
        "global_load_dword %3, %19, %32\n\t"                            \
        "global_load_dword %4, %20, %32\n\t"                            \
        "global_load_dword %5, %21, %32\n\t"                            \
        "global_load_dword %6, %22, %32\n\t"                            \
        "global_load_dword %7, %23, %32\n\t"                            \
        "global_load_dword %8, %24, %32\n\t"                            \
        "global_load_dword %9, %25, %32\n\t"                            \
        "global_load_dword %10, %26, %32\n\t"                           \
        "global_load_dword %11, %27, %32\n\t"                           \
        "global_load_dword %12, %28, %32\n\t"                           \
        "global_load_dword %13, %29, %32\n\t"                           \
        "global_load_dword %14, %30, %32\n\t"                           \
        "global_load_dword %15, %31, %32\n\t"                           \
        "s_waitcnt vmcnt(0)"                                            \
        : "=&v"(P[0]),  "=&v"(P[1]),  "=&v"(P[2]),  "=&v"(P[3]),        \
          "=&v"(P[4]),  "=&v"(P[5]),  "=&v"(P[6]),  "=&v"(P[7]),        \
          "=&v"(P[8]),  "=&v"(P[9]),  "=&v"(P[10]), "=&v"(P[11]),       \
          "=&v"(P[12]), "=&v"(P[13]), "=&v"(P[14]), "=&v"(P[15])        \
        : "v"(VO[0]),  "v"(VO[1]),  "v"(VO[2]),  "v"(VO[3]),            \
          "v"(VO[4]),  "v"(VO[5]),  "v"(VO[6]),  "v"(VO[7]),            \
          "v"(VO[8]),  "v"(VO[9]),  "v"(VO[10]), "v"(VO[11]),           \
          "v"(VO[12]), "v"(VO[13]), "v"(VO[14]), "v"(VO[15]),           \
          "s"(BASE))

// ---- K0: deg zero; W bf16-frag pack (block 0); zb sentinel row ------------
__global__ __launch_bounds__(256) void k_init(
        const float* __restrict__ Wg, int* __restrict__ deg,
        unsigned short* __restrict__ wpk, unsigned short* __restrict__ zb) {
    int tid = threadIdx.x;
    int idx = blockIdx.x * 256 + tid;

    if (idx < NN / 4) ((int4*)deg)[idx] = (int4){0, 0, 0, 0};

    if (blockIdx.x == 0) {
        // frag = nt*256 + kt*64 + quad*16 + lo, elem j = k&7 (verified layout)
#pragma unroll 8
        for (int i = 0; i < 64; i++) {
            int o = i * 256 + tid;
            int j = o & 7, frag = o >> 3;
            int lo = frag & 15, quad = (frag >> 4) & 3;
            int kt = (frag >> 6) & 3, nt = frag >> 8;
            wpk[o] = f32_to_bf16(Wg[(kt * 32 + quad * 8 + j) * 128 + nt * 16 + lo]);
        }
    }
    if (blockIdx.x == 1 && tid < 64)
        ((unsigned*)(zb + (size_t)NN * D))[tid] = 0u;   // sentinel row = 0
}

// ---- K1: PURE count: 1 edge/thread, 12500 waves (machine saturated).
// Solo dur_us == direct measurement of the atomic/scatter floor. Also
// spreads the out-tail zeroing (int4-wide) across all blocks. ---------------
__global__ __launch_bounds__(256) void k_count(
        const int* __restrict__ ei, int* __restrict__ deg,
        int* __restrict__ ell, int* __restrict__ outtail, int tailN) {
    int g = blockIdx.x * 256 + threadIdx.x;   // 0..799999 exactly

    {
        int tail4 = tailN >> 2;
        for (int i = g; i < tail4; i += CNT_BLOCKS * 256)
            ((int4*)outtail)[i] = (int4){0, 0, 0, 0};
        if (g == 0)
            for (int k2 = tail4 << 2; k2 < tailN; k2++) outtail[k2] = 0;
    }

    int s = ei[g];            // coalesced 4B
    int d = ei[NE + g];       // coalesced 4B
    int r = atomicAdd(&deg[d], 1);
    // deg>64 impossible here (Binomial mean 16, 12 sigma); guard anyway
    if (r < 64) ell[(size_t)d * 64 + r] = s;
}

// ---- K2: GEMM ⊕ scale fused: zb = bf16((hW)·rsqrt(deg+1)) directly.
// zf intermediate + k_scale kernel eliminated; arithmetic identical to the
// former store/load round-trip (exact) -> absmax unchanged. -----------------
__global__ __launch_bounds__(256) void k_gemm_scale(
        const float* __restrict__ h, const uint4* __restrict__ wpk4,
        const int* __restrict__ deg, unsigned short* __restrict__ zb) {
    int tid = threadIdx.x;
    int gid = blockIdx.x;
    int w = tid >> 6, lane = tid & 63;
    int quad = lane >> 4, lo = lane & 15;
    int rowBase = gid * 64 + w * 16;
    int rowA = rowBase + lo; if (rowA > NN - 1) rowA = NN - 1;
    const float4* h4 = (const float4*)h;

    bf16x8 af[4];
#pragma unroll
    for (int kt = 0; kt < 4; kt++) {
        float4 u = h4[(size_t)rowA * 32 + kt * 8 + quad * 2];
        float4 v = h4[(size_t)rowA * 32 + kt * 8 + quad * 2 + 1];
        bf16x8 a;
        a[0] = (short)f32_to_bf16(u.x); a[1] = (short)f32_to_bf16(u.y);
        a[2] = (short)f32_to_bf16(u.z); a[3] = (short)f32_to_bf16(u.w);
        a[4] = (short)f32_to_bf16(v.x); a[5] = (short)f32_to_bf16(v.y);
        a[6] = (short)f32_to_bf16(v.z); a[7] = (short)f32_to_bf16(v.w);
        af[kt] = a;
    }

    f32x4 acc[8];
#pragma unroll
    for (int nt = 0; nt < 8; nt++) acc[nt] = (f32x4){0.f, 0.f, 0.f, 0.f};

#pragma unroll
    for (int kt = 0; kt < 4; kt++)
#pragma unroll
        for (int nt = 0; nt < 8; nt++) {
            uint4 tb = wpk4[nt * 256 + kt * 64 + lane];   // coalesced, L1-hit
            acc[nt] = __builtin_amdgcn_mfma_f32_16x16x32_bf16(
                af[kt], __builtin_bit_cast(bf16x8, tb), acc[nt], 0, 0, 0);
        }

#pragma unroll
    for (int reg = 0; reg < 4; reg++) {
        int row = rowBase + quad * 4 + reg;
        if (row < NN) {
            float dn = rsqrtf((float)deg[row] + 1.0f);   // +1 self loop
#pragma unroll
            for (int nt = 0; nt < 8; nt++)
                zb[(size_t)row * D + nt * 16 + lo] = f32_to_bf16(acc[nt][reg] * dn);
        }
    }
}

// ---- K3: gather + LN + tanh over int-ELL rows (round-10 proven) -----------
__global__ __launch_bounds__(256) void k_gather_ln(
        const int* __restrict__ deg, const int* __restrict__ ell,
        const unsigned* __restrict__ zbu,
        const float* __restrict__ bias, const float* __restrict__ gamma,
        const float* __restrict__ beta, float* __restrict__ out) {
    int tid = threadIdx.x;
    int w = tid >> 6, lane = tid & 63;
    int rowBase = blockIdx.x * 16 + w * 4;
    unsigned lane4 = (unsigned)(lane << 2);

    int m0[4]; float dn[4]; unsigned selfz[4]; int v[4];
#pragma unroll
    for (int r = 0; r < 4; r++) {
        int row = rowBase + r;
        int dg = __builtin_amdgcn_readfirstlane(deg[row]);
        dn[r] = rsqrtf((float)dg + 1.0f);
        m0[r] = (dg > 64) ? 64 : dg;
        selfz[r] = zbu[(size_t)row * 64 + lane];
        int t0 = ell[(size_t)row * 64 + lane];   // coalesced 256B row
        v[r] = (lane < m0[r]) ? t0 : NN;         // pad -> zero sentinel row
    }

    float ax[4], ay[4];
#pragma unroll
    for (int r = 0; r < 4; r++) {
        ax[r] = __uint_as_float(selfz[r] << 16);
        ay[r] = __uint_as_float(selfz[r] & 0xFFFF0000u);
    }

    float2 x[4];
#pragma unroll
    for (int r = 0; r < 4; r++) {
        int nb = (m0[r] + 15) >> 4;              // uniform per row
        for (int jb = 0; jb < nb; ++jb) {
            int j = jb << 4;
            unsigned vo[16], p[16];
#pragma unroll
            for (int q = 0; q < 16; q++) {
                int sq = __builtin_amdgcn_readlane(v[r], j + q);
                vo[q] = ((unsigned)sq << 8) + lane4;   // byte offset in zb
            }
            GLD16(p, vo, zbu);
#pragma unroll
            for (int q = 0; q < 16; q++) {
                ax[r] += __uint_as_float(p[q] << 16);
                ay[r] += __uint_as_float(p[q] & 0xFFFF0000u);
            }
        }
        x[r].x = ax[r] * dn[r];
        x[r].y = ay[r] * dn[r];
    }

    float2 bi = ((const float2*)bias)[lane];
    float2 ga = ((const float2*)gamma)[lane];
    float2 be = ((const float2*)beta)[lane];
#pragma unroll
    for (int r = 0; r < 4; r++) {
        int row = rowBase + r;
        float y0 = x[r].x + bi.x;
        float y1 = x[r].y + bi.y;
        float s = y0 + y1;
#pragma unroll
        for (int off = 32; off > 0; off >>= 1) s += __shfl_xor(s, off, 64);
        float m = s * (1.0f / 128.0f);
        float v0f = y0 - m, v1f = y1 - m;
        float vs = v0f * v0f + v1f * v1f;
#pragma unroll
        for (int off = 32; off > 0; off >>= 1) vs += __shfl_xor(vs, off, 64);
        float rstd = rsqrtf(vs * (1.0f / 128.0f) + 1e-5f);
        float2 o;
        o.x = fast_tanh(v0f * rstd * ga.x + be.x);
        o.y = fast_tanh(v1f * rstd * ga.y + be.y);
        *(float2*)&out[(size_t)row * D + lane * 2] = o;
    }
}

extern "C" void kernel_launch(void* const* d_in, const int* in_sizes, int n_in,
                              void* d_out, int out_size, void* d_ws, size_t ws_size,
                              hipStream_t stream) {
    // inputs: t, h, edge_index, batch_size, W, b, gamma, beta
    const float* h     = (const float*)d_in[1];
    const int*   ei    = (const int*)  d_in[2];
    const float* Wg    = (const float*)d_in[4];
    const float* b     = (const float*)d_in[5];
    const float* gamma = (const float*)d_in[6];
    const float* beta  = (const float*)d_in[7];
    float* out = (float*)d_out;

    // workspace layout (~25.8 MB): wpk | deg | ell(int) | zb   (zf removed)
    char* wsb = (char*)d_ws;
    unsigned short* wpk = (unsigned short*)(wsb);            // 32768 B
    int*            deg = (int*)(wsb + 32768);               // NN ints -> 232768
    int*            ell = (int*)(wsb + 232768);              // NN*64 ints -> 13032768
    unsigned short* zb  = (unsigned short*)(wsb + 13032768); // (NN+1)*128 ushorts -> 25833024

    int tailN = out_size - NN * D;                 // int-zeros tail of d_out
    int* outtail = (int*)(out + (size_t)NN * D);

    k_init       <<<64,          256, 0, stream>>>(Wg, deg, wpk, zb);
    k_count      <<<CNT_BLOCKS,  256, 0, stream>>>(ei, deg, ell, outtail, tailN);
    k_gemm_scale <<<GEMM_BLOCKS, 256, 0, stream>>>(h, (const uint4*)wpk, deg, zb);
    k_gather_ln  <<<NN / 16,     256, 0, stream>>>(deg, ell, (const unsigned*)zb, b, gamma, beta, out);
}

// Round 14
// 180.504 us; speedup vs baseline: 1.0922x; 1.0445x over previous
//
#include <hip/hip_runtime.h>
#include <math.h>

#define NN 50000
#define NE 800000
#define D  128
#define NROLES 1564       // 782 count-role + 782 gemm-role, parity interleave

typedef __attribute__((ext_vector_type(8))) short bf16x8;
typedef __attribute__((ext_vector_type(4))) float f32x4;

__device__ __forceinline__ unsigned short f32_to_bf16(float f) {
    unsigned u = __float_as_uint(f);
    u = u + 0x7FFFu + ((u >> 16) & 1u);   // RNE
    return (unsigned short)(u >> 16);
}

// fast tanh: 1 - 2*rcp(e^{2x}+1). Exact at saturation. |err| ~1e-6.
__device__ __forceinline__ float fast_tanh(float x) {
    float e = __expf(2.0f * x);
    return fmaf(-2.0f, __builtin_amdgcn_rcpf(e + 1.0f), 1.0f);
}

// 16 loads issued, NO wait — pairs with a following GLD16 whose vmcnt(0)
// drains all 32 outstanding loads at once (volatile asm blocks keep order).
#define GLD16_NOWAIT(P, VO, BASE)                                       \
    asm volatile(                                                       \
        "global_load_dword %0, %16, %32\n\t"                            \
        "global_load_dword %1, %17, %32\n\t"                            \
        "global_load_dword %2, %18, %32\n\t"                            \
        "global_load_dword %3, %19, %32\n\t"                            \
        "global_load_dword %4, %20, %32\n\t"                            \
        "global_load_dword %5, %21, %32\n\t"                            \
        "global_load_dword %6, %22, %32\n\t"                            \
        "global_load_dword %7, %23, %32\n\t"                            \
        "global_load_dword %8, %24, %32\n\t"                            \
        "global_load_dword %9, %25, %32\n\t"                            \
        "global_load_dword %10, %26, %32\n\t"                           \
        "global_load_dword %11, %27, %32\n\t"                           \
        "global_load_dword %12, %28, %32\n\t"                           \
        "global_load_dword %13, %29, %32\n\t"                           \
        "global_load_dword %14, %30, %32\n\t"                           \
        "global_load_dword %15, %31, %32"                               \
        : "=&v"(P[0]),  "=&v"(P[1]),  "=&v"(P[2]),  "=&v"(P[3]),        \
          "=&v"(P[4]),  "=&v"(P[5]),  "=&v"(P[6]),  "=&v"(P[7]),        \
          "=&v"(P[8]),  "=&v"(P[9]),  "=&v"(P[10]), "=&v"(P[11]),       \
          "=&v"(P[12]), "=&v"(P[13]), "=&v"(P[14]), "=&v"(P[15])        \
        : "v"(VO[0]),  "v"(VO[1]),  "v"(VO[2]),  "v"(VO[3]),            \
          "v"(VO[4]),  "v"(VO[5]),  "v"(VO[6]),  "v"(VO[7]),            \
          "v"(VO[8]),  "v"(VO[9]),  "v"(VO[10]), "v"(VO[11]),           \
          "v"(VO[12]), "v"(VO[13]), "v"(VO[14]), "v"(VO[15]),           \
          "s"(BASE))

// 16 loads + vmcnt(0): drains these AND any prior outstanding loads.
#define GLD16(P, VO, BASE)                                              \
    asm volatile(                                                       \
        "global_load_dword %0, %16, %32\n\t"                            \
        "global_load_dword %1, %17, %32\n\t"                            \
        "global_load_dword %2, %18, %32\n\t"                            \
        "global_load_dword %3, %19, %32\n\t"                            \
        "global_load_dword %4, %20, %32\n\t"                            \
        "global_load_dword %5, %21, %32\n\t"                            \
        "global_load_dword %6, %22, %32\n\t"                            \
        "global_load_dword %7, %23, %32\n\t"                            \
        "global_load_dword %8, %24, %32\n\t"                            \
        "global_load_dword %9, %25, %32\n\t"                            \
        "global_load_dword %10, %26, %32\n\t"                           \
        "global_load_dword %11, %27, %32\n\t"                           \
        "global_load_dword %12, %28, %32\n\t"                           \
        "global_load_dword %13, %29, %32\n\t"                           \
        "global_load_dword %14, %30, %32\n\t"                           \
        "global_load_dword %15, %31, %32\n\t"                           \
        "s_waitcnt vmcnt(0)"                                            \
        : "=&v"(P[0]),  "=&v"(P[1]),  "=&v"(P[2]),  "=&v"(P[3]),        \
          "=&v"(P[4]),  "=&v"(P[5]),  "=&v"(P[6]),  "=&v"(P[7]),        \
          "=&v"(P[8]),  "=&v"(P[9]),  "=&v"(P[10]), "=&v"(P[11]),       \
          "=&v"(P[12]), "=&v"(P[13]), "=&v"(P[14]), "=&v"(P[15])        \
        : "v"(VO[0]),  "v"(VO[1]),  "v"(VO[2]),  "v"(VO[3]),            \
          "v"(VO[4]),  "v"(VO[5]),  "v"(VO[6]),  "v"(VO[7]),            \
          "v"(VO[8]),  "v"(VO[9]),  "v"(VO[10]), "v"(VO[11]),           \
          "v"(VO[12]), "v"(VO[13]), "v"(VO[14]), "v"(VO[15]),           \
          "s"(BASE))

// ---- K0: deg[0..NN] zero; W bf16-frag pack (block 0); zb sentinel row -----
__global__ __launch_bounds__(256) void k_init(
        const float* __restrict__ Wg, int* __restrict__ deg,
        unsigned short* __restrict__ wpk, unsigned short* __restrict__ zb) {
    int tid = threadIdx.x;
    int idx = blockIdx.x * 256 + tid;

    if (idx < NN / 4) ((int4*)deg)[idx] = (int4){0, 0, 0, 0};
    if (idx == NN / 4) deg[NN] = 0;            // sentinel node degree = 0

    if (blockIdx.x == 0) {
        // frag = nt*256 + kt*64 + quad*16 + lo, elem j = k&7 (verified layout)
#pragma unroll 8
        for (int i = 0; i < 64; i++) {
            int o = i * 256 + tid;
            int j = o & 7, frag = o >> 3;
            int lo = frag & 15, quad = (frag >> 4) & 3;
            int kt = (frag >> 6) & 3, nt = frag >> 8;
            wpk[o] = f32_to_bf16(Wg[(kt * 32 + quad * 8 + j) * 128 + nt * 16 + lo]);
        }
    }
    if (blockIdx.x == 1 && tid < 64)
        ((unsigned*)(zb + (size_t)NN * D))[tid] = 0u;   // sentinel row = 0
}

// ---- K1: count(atomics->ELL) + GEMM interleaved by parity (round-10 proven
// overlap: GEMM hides under the atomic stream's latency shadow). GEMM writes
// UNSCALED bf16 z (no deg dep); dinv moves to the gather (round-0 numerics).
__global__ __launch_bounds__(256) void k_count_gemm(
        const float* __restrict__ h, const uint4* __restrict__ wpk4,
        const int* __restrict__ ei, int* __restrict__ deg,
        int* __restrict__ ell, unsigned short* __restrict__ zb,
        int* __restrict__ outtail, int tailN) {
    int tid = threadIdx.x;
    int bid = blockIdx.x;

    // out-tail zeroing: all blocks, int4-wide
    {
        int gt = bid * 256 + tid;
        int tail4 = tailN >> 2;
        for (int i = gt; i < tail4; i += NROLES * 256)
            ((int4*)outtail)[i] = (int4){0, 0, 0, 0};
        if (gt == 0)
            for (int k2 = tail4 << 2; k2 < tailN; k2++) outtail[k2] = 0;
    }

    if (bid & 1) {
        // ---- count role: 782 blocks, 4 edges/thread (round-10 proven) ----
        int g = (bid >> 1) * 256 + tid;
        if (g < NE / 4) {
            int4 s4 = ((const int4*)ei)[g];
            int4 d4 = ((const int4*)(ei + NE))[g];
            int r0 = atomicAdd(&deg[d4.x], 1);
            int r1 = atomicAdd(&deg[d4.y], 1);
            int r2 = atomicAdd(&deg[d4.z], 1);
            int r3 = atomicAdd(&deg[d4.w], 1);
            // deg>64 impossible here (Binomial mean 16, 12 sigma); guard anyway
            if (r0 < 64) ell[(size_t)d4.x * 64 + r0] = s4.x;
            if (r1 < 64) ell[(size_t)d4.y * 64 + r1] = s4.y;
            if (r2 < 64) ell[(size_t)d4.z * 64 + r2] = s4.z;
            if (r3 < 64) ell[(size_t)d4.w * 64 + r3] = s4.w;
        }
        return;
    }

    // ---- GEMM role: 782 blocks, zb = bf16(hW) UNSCALED ----
    int gid = bid >> 1;
    int w = tid >> 6, lane = tid & 63;
    int quad = lane >> 4, lo = lane & 15;
    int rowBase = gid * 64 + w * 16;
    int rowA = rowBase + lo; if (rowA > NN - 1) rowA = NN - 1;
    const float4* h4 = (const float4*)h;

    bf16x8 af[4];
#pragma unroll
    for (int kt = 0; kt < 4; kt++) {
        float4 u = h4[(size_t)rowA * 32 + kt * 8 + quad * 2];
        float4 v = h4[(size_t)rowA * 32 + kt * 8 + quad * 2 + 1];
        bf16x8 a;
        a[0] = (short)f32_to_bf16(u.x); a[1] = (short)f32_to_bf16(u.y);
        a[2] = (short)f32_to_bf16(u.z); a[3] = (short)f32_to_bf16(u.w);
        a[4] = (short)f32_to_bf16(v.x); a[5] = (short)f32_to_bf16(v.y);
        a[6] = (short)f32_to_bf16(v.z); a[7] = (short)f32_to_bf16(v.w);
        af[kt] = a;
    }

    f32x4 acc[8];
#pragma unroll
    for (int nt = 0; nt < 8; nt++) acc[nt] = (f32x4){0.f, 0.f, 0.f, 0.f};

#pragma unroll
    for (int kt = 0; kt < 4; kt++)
#pragma unroll
        for (int nt = 0; nt < 8; nt++) {
            uint4 tb = wpk4[nt * 256 + kt * 64 + lane];   // coalesced, L1-hit
            acc[nt] = __builtin_amdgcn_mfma_f32_16x16x32_bf16(
                af[kt], __builtin_bit_cast(bf16x8, tb), acc[nt], 0, 0, 0);
        }

#pragma unroll
    for (int reg = 0; reg < 4; reg++) {
        int row = rowBase + quad * 4 + reg;
        if (row < NN) {
#pragma unroll
            for (int nt = 0; nt < 8; nt++)
                zb[(size_t)row * D + nt * 16 + lo] = f32_to_bf16(acc[nt][reg]);
        }
    }
}

// ---- K2: gather + LN + tanh. Per-neighbor dinv (round-0 numerics):
// deg[s] gathered via GLD16_NOWAIT, z[s] via GLD16 — all 32 loads share one
// vmcnt(0) drain. acc = sum fmaf(rsqrt(deg[s]+1), z[s]); final x dinv[row]. -
__global__ __launch_bounds__(256) void k_gather_ln(
        const int* __restrict__ deg, const int* __restrict__ ell,
        const unsigned* __restrict__ zbu,
        const float* __restrict__ bias, const float* __restrict__ gamma,
        const float* __restrict__ beta, float* __restrict__ out) {
    int tid = threadIdx.x;
    int w = tid >> 6, lane = tid & 63;
    int rowBase = blockIdx.x * 16 + w * 4;
    unsigned lane4 = (unsigned)(lane << 2);

    int m0[4]; float dn[4]; unsigned selfz[4]; int v[4];
#pragma unroll
    for (int r = 0; r < 4; r++) {
        int row = rowBase + r;
        int dg = __builtin_amdgcn_readfirstlane(deg[row]);
        dn[r] = rsqrtf((float)dg + 1.0f);
        m0[r] = (dg > 64) ? 64 : dg;
        selfz[r] = zbu[(size_t)row * 64 + lane];
        int t0 = ell[(size_t)row * 64 + lane];   // coalesced 256B row
        v[r] = (lane < m0[r]) ? t0 : NN;         // pad -> zero sentinel row
    }

    float ax[4], ay[4];
#pragma unroll
    for (int r = 0; r < 4; r++) {
        // self term: dinv[row] * z[row]  (z unscaled bf16)
        ax[r] = dn[r] * __uint_as_float(selfz[r] << 16);
        ay[r] = dn[r] * __uint_as_float(selfz[r] & 0xFFFF0000u);
    }

    float2 x[4];
#pragma unroll
    for (int r = 0; r < 4; r++) {
        int nb = (m0[r] + 15) >> 4;              // uniform per row
        for (int jb = 0; jb < nb; ++jb) {
            int j = jb << 4;
            unsigned vo[16], vod[16], dgq[16], p[16];
#pragma unroll
            for (int q = 0; q < 16; q++) {
                int sq = __builtin_amdgcn_readlane(v[r], j + q);
                vo[q]  = ((unsigned)sq << 8) + lane4;   // byte off in zb
                vod[q] = (unsigned)sq << 2;             // byte off in deg
            }
            GLD16_NOWAIT(dgq, vod, deg);     // issue deg gathers (L2-hot)
            GLD16(p, vo, zbu);               // z gathers; vmcnt(0) drains all
            float dnq[16];
#pragma unroll
            for (int q = 0; q < 16; q++)
                dnq[q] = rsqrtf((float)(int)dgq[q] + 1.0f);
#pragma unroll
            for (int q = 0; q < 16; q++) {
                ax[r] = fmaf(dnq[q], __uint_as_float(p[q] << 16), ax[r]);
                ay[r] = fmaf(dnq[q], __uint_as_float(p[q] & 0xFFFF0000u), ay[r]);
            }
        }
        x[r].x = ax[r] * dn[r];
        x[r].y = ay[r] * dn[r];
    }

    float2 bi = ((const float2*)bias)[lane];
    float2 ga = ((const float2*)gamma)[lane];
    float2 be = ((const float2*)beta)[lane];
#pragma unroll
    for (int r = 0; r < 4; r++) {
        int row = rowBase + r;
        float y0 = x[r].x + bi.x;
        float y1 = x[r].y + bi.y;
        float s = y0 + y1;
#pragma unroll
        for (int off = 32; off > 0; off >>= 1) s += __shfl_xor(s, off, 64);
        float m = s * (1.0f / 128.0f);
        float v0f = y0 - m, v1f = y1 - m;
        float vs = v0f * v0f + v1f * v1f;
#pragma unroll
        for (int off = 32; off > 0; off >>= 1) vs += __shfl_xor(vs, off, 64);
        float rstd = rsqrtf(vs * (1.0f / 128.0f) + 1e-5f);
        float2 o;
        o.x = fast_tanh(v0f * rstd * ga.x + be.x);
        o.y = fast_tanh(v1f * rstd * ga.y + be.y);
        *(float2*)&out[(size_t)row * D + lane * 2] = o;
    }
}

extern "C" void kernel_launch(void* const* d_in, const int* in_sizes, int n_in,
                              void* d_out, int out_size, void* d_ws, size_t ws_size,
                              hipStream_t stream) {
    // inputs: t, h, edge_index, batch_size, W, b, gamma, beta
    const float* h     = (const float*)d_in[1];
    const int*   ei    = (const int*)  d_in[2];
    const float* Wg    = (const float*)d_in[4];
    const float* b     = (const float*)d_in[5];
    const float* gamma = (const float*)d_in[6];
    const float* beta  = (const float*)d_in[7];
    float* out = (float*)d_out;

    // workspace layout (~25.9 MB): wpk | deg(NN+1) | ell(int) | zb(bf16,unscaled)
    char* wsb = (char*)d_ws;
    unsigned short* wpk = (unsigned short*)(wsb);            // 32768 B
    int*            deg = (int*)(wsb + 32768);               // (NN+1) ints -> +204800
    int*            ell = (int*)(wsb + 237568);              // NN*64 ints -> +12800000
    unsigned short* zb  = (unsigned short*)(wsb + 13037568); // (NN+1)*128 ushorts

    int tailN = out_size - NN * D;                 // int-zeros tail of d_out
    int* outtail = (int*)(out + (size_t)NN * D);

    k_init       <<<64,      256, 0, stream>>>(Wg, deg, wpk, zb);
    k_count_gemm <<<NROLES,  256, 0, stream>>>(h, (const uint4*)wpk, ei, deg, ell, zb, outtail, tailN);
    k_gather_ln  <<<NN / 16, 256, 0, stream>>>(deg, ell, (const unsigned*)zb, b, gamma, beta, out);
}

// Round 15
// 178.501 us; speedup vs baseline: 1.1045x; 1.0112x over previous
//
#include <hip/hip_runtime.h>
#include <math.h>

#define NN 50000
#define NE 800000
#define D  128
#define NROLES 1564       // 782 count-role + 782 gemm-role, parity interleave

typedef __attribute__((ext_vector_type(8))) short bf16x8;
typedef __attribute__((ext_vector_type(4))) float f32x4;

__device__ __forceinline__ unsigned short f32_to_bf16(float f) {
    unsigned u = __float_as_uint(f);
    u = u + 0x7FFFu + ((u >> 16) & 1u);   // RNE
    return (unsigned short)(u >> 16);
}

// fast tanh: 1 - 2*rcp(e^{2x}+1). Exact at saturation. |err| ~1e-6.
__device__ __forceinline__ float fast_tanh(float x) {
    float e = __expf(2.0f * x);
    return fmaf(-2.0f, __builtin_amdgcn_rcpf(e + 1.0f), 1.0f);
}

// 16 loads issued, NO wait — pairs with a following GLD16 whose vmcnt(0)
// drains all 32 outstanding loads at once (volatile asm blocks keep order).
#define GLD16_NOWAIT(P, VO, BASE)                                       \
    asm volatile(                                                       \
        "global_load_dword %0, %16, %32\n\t"                            \
        "global_load_dword %1, %17, %32\n\t"                            \
        "global_load_dword %2, %18, %32\n\t"                            \
        "global_load_dword %3, %19, %32\n\t"                            \
        "global_load_dword %4, %20, %32\n\t"                            \
        "global_load_dword %5, %21, %32\n\t"                            \
        "global_load_dword %6, %22, %32\n\t"                            \
        "global_load_dword %7, %23, %32\n\t"                            \
        "global_load_dword %8, %24, %32\n\t"                            \
        "global_load_dword %9, %25, %32\n\t"                            \
        "global_load_dword %10, %26, %32\n\t"                           \
        "global_load_dword %11, %27, %32\n\t"                           \
        "global_load_dword %12, %28, %32\n\t"                           \
        "global_load_dword %13, %29, %32\n\t"                           \
        "global_load_dword %14, %30, %32\n\t"                           \
        "global_load_dword %15, %31, %32"                               \
        : "=&v"(P[0]),  "=&v"(P[1]),  "=&v"(P[2]),  "=&v"(P[3]),        \
          "=&v"(P[4]),  "=&v"(P[5]),  "=&v"(P[6]),  "=&v"(P[7]),        \
          "=&v"(P[8]),  "=&v"(P[9]),  "=&v"(P[10]), "=&v"(P[11]),       \
          "=&v"(P[12]), "=&v"(P[13]), "=&v"(P[14]), "=&v"(P[15])        \
        : "v"(VO[0]),  "v"(VO[1]),  "v"(VO[2]),  "v"(VO[3]),            \
          "v"(VO[4]),  "v"(VO[5]),  "v"(VO[6]),  "v"(VO[7]),            \
          "v"(VO[8]),  "v"(VO[9]),  "v"(VO[10]), "v"(VO[11]),           \
          "v"(VO[12]), "v"(VO[13]), "v"(VO[14]), "v"(VO[15]),           \
          "s"(BASE))

// 16 loads + vmcnt(0): drains these AND any prior outstanding loads.
#define GLD16(P, VO, BASE)                                              \
    asm volatile(                                                       \
        "global_load_dword %0, %16, %32\n\t"                            \
        "global_load_dword %1, %17, %32\n\t"                            \
        "global_load_dword %2, %18, %32\n\t"                            \
        "global_load_dword %3, %19, %32\n\t"                            \
        "global_load_dword %4, %20, %32\n\t"                            \
        "global_load_dword %5, %21, %32\n\t"                            \
        "global_load_dword %6, %22, %32\n\t"                            \
        "global_load_dword %7, %23, %32\n\t"                            \
        "global_load_dword %8, %24, %32\n\t"                            \
        "global_load_dword %9, %25, %32\n\t"                            \
        "global_load_dword %10, %26, %32\n\t"                           \
        "global_load_dword %11, %27, %32\n\t"                           \
        "global_load_dword %12, %28, %32\n\t"                           \
        "global_load_dword %13, %29, %32\n\t"                           \
        "global_load_dword %14, %30, %32\n\t"                           \
        "global_load_dword %15, %31, %32\n\t"                           \
        "s_waitcnt vmcnt(0)"                                            \
        : "=&v"(P[0]),  "=&v"(P[1]),  "=&v"(P[2]),  "=&v"(P[3]),        \
          "=&v"(P[4]),  "=&v"(P[5]),  "=&v"(P[6]),  "=&v"(P[7]),        \
          "=&v"(P[8]),  "=&v"(P[9]),  "=&v"(P[10]), "=&v"(P[11]),       \
          "=&v"(P[12]), "=&v"(P[13]), "=&v"(P[14]), "=&v"(P[15])        \
        : "v"(VO[0]),  "v"(VO[1]),  "v"(VO[2]),  "v"(VO[3]),            \
          "v"(VO[4]),  "v"(VO[5]),  "v"(VO[6]),  "v"(VO[7]),            \
          "v"(VO[8]),  "v"(VO[9]),  "v"(VO[10]), "v"(VO[11]),           \
          "v"(VO[12]), "v"(VO[13]), "v"(VO[14]), "v"(VO[15]),           \
          "s"(BASE))

// ---- K0: deg[0..NN] zero; W bf16-frag pack (block 0); zb sentinel row -----
__global__ __launch_bounds__(256) void k_init(
        const float* __restrict__ Wg, int* __restrict__ deg,
        unsigned short* __restrict__ wpk, unsigned short* __restrict__ zb) {
    int tid = threadIdx.x;
    int idx = blockIdx.x * 256 + tid;

    if (idx < NN / 4) ((int4*)deg)[idx] = (int4){0, 0, 0, 0};
    if (idx == NN / 4) deg[NN] = 0;            // sentinel node degree = 0

    if (blockIdx.x == 0) {
        // frag = nt*256 + kt*64 + quad*16 + lo, elem j = k&7 (verified layout)
#pragma unroll 8
        for (int i = 0; i < 64; i++) {
            int o = i * 256 + tid;
            int j = o & 7, frag = o >> 3;
            int lo = frag & 15, quad = (frag >> 4) & 3;
            int kt = (frag >> 6) & 3, nt = frag >> 8;
            wpk[o] = f32_to_bf16(Wg[(kt * 32 + quad * 8 + j) * 128 + nt * 16 + lo]);
        }
    }
    if (blockIdx.x == 1 && tid < 64)
        ((unsigned*)(zb + (size_t)NN * D))[tid] = 0u;   // sentinel row = 0
}

// ---- K1: count(atomics->ELL) + GEMM interleaved by parity (proven overlap:
// GEMM hides under the atomic stream's latency shadow). GEMM writes UNSCALED
// bf16 z; per-neighbor dinv applied in the gather (round-0 numerics). -------
__global__ __launch_bounds__(256) void k_count_gemm(
        const float* __restrict__ h, const uint4* __restrict__ wpk4,
        const int* __restrict__ ei, int* __restrict__ deg,
        int* __restrict__ ell, unsigned short* __restrict__ zb,
        int* __restrict__ outtail, int tailN) {
    int tid = threadIdx.x;
    int bid = blockIdx.x;

    // out-tail zeroing: all blocks, int4-wide
    {
        int gt = bid * 256 + tid;
        int tail4 = tailN >> 2;
        for (int i = gt; i < tail4; i += NROLES * 256)
            ((int4*)outtail)[i] = (int4){0, 0, 0, 0};
        if (gt == 0)
            for (int k2 = tail4 << 2; k2 < tailN; k2++) outtail[k2] = 0;
    }

    if (bid & 1) {
        // ---- count role: 782 blocks, 4 edges/thread (round-10 proven) ----
        int g = (bid >> 1) * 256 + tid;
        if (g < NE / 4) {
            int4 s4 = ((const int4*)ei)[g];
            int4 d4 = ((const int4*)(ei + NE))[g];
            int r0 = atomicAdd(&deg[d4.x], 1);
            int r1 = atomicAdd(&deg[d4.y], 1);
            int r2 = atomicAdd(&deg[d4.z], 1);
            int r3 = atomicAdd(&deg[d4.w], 1);
            // deg>64 impossible here (Binomial mean 16, 12 sigma); guard anyway
            if (r0 < 64) ell[(size_t)d4.x * 64 + r0] = s4.x;
            if (r1 < 64) ell[(size_t)d4.y * 64 + r1] = s4.y;
            if (r2 < 64) ell[(size_t)d4.z * 64 + r2] = s4.z;
            if (r3 < 64) ell[(size_t)d4.w * 64 + r3] = s4.w;
        }
        return;
    }

    // ---- GEMM role: 782 blocks, zb = bf16(hW) UNSCALED ----
    int gid = bid >> 1;
    int w = tid >> 6, lane = tid & 63;
    int quad = lane >> 4, lo = lane & 15;
    int rowBase = gid * 64 + w * 16;
    int rowA = rowBase + lo; if (rowA > NN - 1) rowA = NN - 1;
    const float4* h4 = (const float4*)h;

    bf16x8 af[4];
#pragma unroll
    for (int kt = 0; kt < 4; kt++) {
        float4 u = h4[(size_t)rowA * 32 + kt * 8 + quad * 2];
        float4 v = h4[(size_t)rowA * 32 + kt * 8 + quad * 2 + 1];
        bf16x8 a;
        a[0] = (short)f32_to_bf16(u.x); a[1] = (short)f32_to_bf16(u.y);
        a[2] = (short)f32_to_bf16(u.z); a[3] = (short)f32_to_bf16(u.w);
        a[4] = (short)f32_to_bf16(v.x); a[5] = (short)f32_to_bf16(v.y);
        a[6] = (short)f32_to_bf16(v.z); a[7] = (short)f32_to_bf16(v.w);
        af[kt] = a;
    }

    f32x4 acc[8];
#pragma unroll
    for (int nt = 0; nt < 8; nt++) acc[nt] = (f32x4){0.f, 0.f, 0.f, 0.f};

#pragma unroll
    for (int kt = 0; kt < 4; kt++)
#pragma unroll
        for (int nt = 0; nt < 8; nt++) {
            uint4 tb = wpk4[nt * 256 + kt * 64 + lane];   // coalesced, L1-hit
            acc[nt] = __builtin_amdgcn_mfma_f32_16x16x32_bf16(
                af[kt], __builtin_bit_cast(bf16x8, tb), acc[nt], 0, 0, 0);
        }

#pragma unroll
    for (int reg = 0; reg < 4; reg++) {
        int row = rowBase + quad * 4 + reg;
        if (row < NN) {
#pragma unroll
            for (int nt = 0; nt < 8; nt++)
                zb[(size_t)row * D + nt * 16 + lo] = f32_to_bf16(acc[nt][reg]);
        }
    }
}

// ---- K2: dinv table: dinv[i] = rsqrtf(deg[i]+1), i in [0, NN]. Tiny
// streaming pass (400 KB) that deletes 800K rsqrt+cvt from the gather. ------
__global__ __launch_bounds__(256) void k_dinv(
        const int* __restrict__ deg, float* __restrict__ dinv) {
    int i = blockIdx.x * 256 + threadIdx.x;
    if (i <= NN) dinv[i] = rsqrtf((float)deg[i] + 1.0f);
}

// ---- K3: gather + LN + tanh. dinv[s] TABLE LOOKUP through GLD16_NOWAIT
// (replaces per-neighbor rsqrt+cvt — gather was VALU-bound at 70%).
// Same f32 values as recompute -> bit-identical summation. ------------------
__global__ __launch_bounds__(256) void k_gather_ln(
        const int* __restrict__ deg, const float* __restrict__ dinv,
        const int* __restrict__ ell, const unsigned* __restrict__ zbu,
        const float* __restrict__ bias, const float* __restrict__ gamma,
        const float* __restrict__ beta, float* __restrict__ out) {
    int tid = threadIdx.x;
    int w = tid >> 6, lane = tid & 63;
    int rowBase = blockIdx.x * 16 + w * 4;
    unsigned lane4 = (unsigned)(lane << 2);

    int m0[4]; float dn[4]; unsigned selfz[4]; int v[4];
#pragma unroll
    for (int r = 0; r < 4; r++) {
        int row = rowBase + r;
        int dg = __builtin_amdgcn_readfirstlane(deg[row]);
        dn[r] = dinv[row];                       // table (same rsqrtf value)
        m0[r] = (dg > 64) ? 64 : dg;
        selfz[r] = zbu[(size_t)row * 64 + lane];
        int t0 = ell[(size_t)row * 64 + lane];   // coalesced 256B row
        v[r] = (lane < m0[r]) ? t0 : NN;         // pad -> zero sentinel row
    }

    float ax[4], ay[4];
#pragma unroll
    for (int r = 0; r < 4; r++) {
        // self term: dinv[row] * z[row]  (z unscaled bf16)
        ax[r] = dn[r] * __uint_as_float(selfz[r] << 16);
        ay[r] = dn[r] * __uint_as_float(selfz[r] & 0xFFFF0000u);
    }

    float2 x[4];
#pragma unroll
    for (int r = 0; r < 4; r++) {
        int nb = (m0[r] + 15) >> 4;              // uniform per row
        for (int jb = 0; jb < nb; ++jb) {
            int j = jb << 4;
            unsigned vo[16], vod[16], dq[16], p[16];
#pragma unroll
            for (int q = 0; q < 16; q++) {
                int sq = __builtin_amdgcn_readlane(v[r], j + q);
                vo[q]  = ((unsigned)sq << 8) + lane4;   // byte off in zb
                vod[q] = (unsigned)sq << 2;             // byte off in dinv
            }
            GLD16_NOWAIT(dq, vod, dinv);     // dinv gathers (L2-hot 200KB)
            GLD16(p, vo, zbu);               // z gathers; vmcnt(0) drains all
#pragma unroll
            for (int q = 0; q < 16; q++) {
                float dnq = __uint_as_float(dq[q]);
                ax[r] = fmaf(dnq, __uint_as_float(p[q] << 16), ax[r]);
                ay[r] = fmaf(dnq, __uint_as_float(p[q] & 0xFFFF0000u), ay[r]);
            }
        }
        x[r].x = ax[r] * dn[r];
        x[r].y = ay[r] * dn[r];
    }

    float2 bi = ((const float2*)bias)[lane];
    float2 ga = ((const float2*)gamma)[lane];
    float2 be = ((const float2*)beta)[lane];
#pragma unroll
    for (int r = 0; r < 4; r++) {
        int row = rowBase + r;
        float y0 = x[r].x + bi.x;
        float y1 = x[r].y + bi.y;
        float s = y0 + y1;
#pragma unroll
        for (int off = 32; off > 0; off >>= 1) s += __shfl_xor(s, off, 64);
        float m = s * (1.0f / 128.0f);
        float v0f = y0 - m, v1f = y1 - m;
        float vs = v0f * v0f + v1f * v1f;
#pragma unroll
        for (int off = 32; off > 0; off >>= 1) vs += __shfl_xor(vs, off, 64);
        float rstd = rsqrtf(vs * (1.0f / 128.0f) + 1e-5f);
        float2 o;
        o.x = fast_tanh(v0f * rstd * ga.x + be.x);
        o.y = fast_tanh(v1f * rstd * ga.y + be.y);
        *(float2*)&out[(size_t)row * D + lane * 2] = o;
    }
}

extern "C" void kernel_launch(void* const* d_in, const int* in_sizes, int n_in,
                              void* d_out, int out_size, void* d_ws, size_t ws_size,
                              hipStream_t stream) {
    // inputs: t, h, edge_index, batch_size, W, b, gamma, beta
    const float* h     = (const float*)d_in[1];
    const int*   ei    = (const int*)  d_in[2];
    const float* Wg    = (const float*)d_in[4];
    const float* b     = (const float*)d_in[5];
    const float* gamma = (const float*)d_in[6];
    const float* beta  = (const float*)d_in[7];
    float* out = (float*)d_out;

    // workspace (~26.3 MB): wpk | deg(NN+1) | dinv(NN+1) | ell(int) | zb
    char* wsb = (char*)d_ws;
    unsigned short* wpk  = (unsigned short*)(wsb);            // 32768 B
    int*            deg  = (int*)(wsb + 32768);               // (NN+1) ints
    float*          dinv = (float*)(wsb + 237632);            // (NN+1) floats
    int*            ell  = (int*)(wsb + 437696);              // NN*64 ints
    unsigned short* zb   = (unsigned short*)(wsb + 13237696); // (NN+1)*128 ushorts

    int tailN = out_size - NN * D;                 // int-zeros tail of d_out
    int* outtail = (int*)(out + (size_t)NN * D);

    k_init       <<<64,      256, 0, stream>>>(Wg, deg, wpk, zb);
    k_count_gemm <<<NROLES,  256, 0, stream>>>(h, (const uint4*)wpk, ei, deg, ell, zb, outtail, tailN);
    k_dinv       <<<196,     256, 0, stream>>>(deg, dinv);
    k_gather_ln  <<<NN / 16, 256, 0, stream>>>(deg, dinv, ell, (const unsigned*)zb, b, gamma, beta, out);
}